// Round 1
// baseline (1679.988 us; speedup 1.0000x reference)
//
#include <hip/hip_runtime.h>
#include <math.h>

#define G 4
#define H 64
#define T 1000
#define B 32
#define F 256       // G*H
#define ROWS (B*T)  // 32000

__device__ __forceinline__ float sigm(float x) {
    return 1.f / (1.f + __expf(-x));
}
__device__ __forceinline__ float tanh_f(float x) {
    // 2*sigmoid(2x)-1 ; safe at |x| large (div by inf -> 0)
    return 2.f / (1.f + __expf(-2.f * x)) - 1.f;
}

// One block per (g,b) sequence. 256 threads: thread k owns gate row k
// (rows 0-63 = i, 64-127 = f, 128-191 = g[tanh], 192-255 = o).
// Weights for both mat-vecs live in VGPRs (128 floats/thread).
// h exchanged via LDS; x_t double-buffered in LDS with 2-deep register prefetch.
template<int LAYER>
__global__ __launch_bounds__(256, 1)
void rec_kernel(const float* __restrict__ xin,   // (B,T,256); layer2: == out (BN1 fused on read)
                const float* __restrict__ Wih,   // (G,256,64)
                const float* __restrict__ Whh,   // (G,256,64)
                const float* __restrict__ bias,  // (G,256)
                const float* __restrict__ bnac,  // [512] a|c (layer2 only)
                float* __restrict__ out)         // (B,T,256)
{
    const int g = blockIdx.x & 3;
    const int b = blockIdx.x >> 2;
    const int k = threadIdx.x;

    __shared__ __align__(16) float xsh[2][64];
    __shared__ __align__(16) float hsh[64];
    __shared__ __align__(16) float gsh[256];

    // ---- preload weights into registers (fully unrolled -> stays in VGPRs)
    float wih[64], whh[64];
    {
        const float4* wi = (const float4*)(Wih + (size_t)(g * 256 + k) * 64);
        const float4* wh = (const float4*)(Whh + (size_t)(g * 256 + k) * 64);
        #pragma unroll
        for (int i = 0; i < 16; ++i) {
            float4 v = wi[i];
            wih[4*i] = v.x; wih[4*i+1] = v.y; wih[4*i+2] = v.z; wih[4*i+3] = v.w;
            float4 u = wh[i];
            whh[4*i] = u.x; whh[4*i+1] = u.y; whh[4*i+2] = u.z; whh[4*i+3] = u.w;
        }
    }
    const float bk = bias[g * 256 + k];

    const long rowbase = (long)b * T;
    const int  colbase = g * 64;

    // per-column state (only lanes k<64 use these)
    float c = 0.f, af = 1.f, cf = 0.f;
    float xa = 0.f, xb = 0.f;   // register prefetch pipeline: xa=x[t+1], xb=x[t+2]

    if (k < 64) {
        if (LAYER == 2) { af = bnac[colbase + k]; cf = bnac[256 + colbase + k]; }
        hsh[k] = 0.f;
        float x0 = xin[(rowbase + 0) * 256 + colbase + k];
        xsh[0][k] = (LAYER == 2) ? fmaf(x0, af, cf) : x0;
        int t1 = (1 < T) ? 1 : T - 1;
        int t2 = (2 < T) ? 2 : T - 1;
        xa = xin[(rowbase + t1) * 256 + colbase + k];
        xb = xin[(rowbase + t2) * 256 + colbase + k];
    }
    __syncthreads();

    for (int t = 0; t < T; ++t) {
        const int cur = t & 1;

        // issue prefetch of x[t+3] early (consumed 2 iterations later)
        float xn = 0.f;
        if (k < 64) {
            int tp = t + 3; if (tp > T - 1) tp = T - 1;
            xn = xin[(rowbase + tp) * 256 + colbase + k];
        }

        // gates: W_ih @ x_t + W_hh @ h_{t-1} + b   (4 parallel accumulators)
        const float* xs = xsh[cur];
        float a0 = 0.f, a1 = 0.f, a2 = 0.f, a3 = 0.f;
        #pragma unroll
        for (int i = 0; i < 64; i += 4) {
            a0 = fmaf(wih[i],     xs[i],     a0);
            a1 = fmaf(wih[i + 1], xs[i + 1], a1);
            a2 = fmaf(wih[i + 2], xs[i + 2], a2);
            a3 = fmaf(wih[i + 3], xs[i + 3], a3);
        }
        #pragma unroll
        for (int j = 0; j < 64; j += 4) {
            a0 = fmaf(whh[j],     hsh[j],     a0);
            a1 = fmaf(whh[j + 1], hsh[j + 1], a1);
            a2 = fmaf(whh[j + 2], hsh[j + 2], a2);
            a3 = fmaf(whh[j + 3], hsh[j + 3], a3);
        }
        const float acc = bk + ((a0 + a1) + (a2 + a3));

        // activation (wave-uniform branch: wave 2 is tanh)
        const float act = (k >= 128 && k < 192) ? tanh_f(acc) : sigm(acc);
        gsh[k] = act;
        __syncthreads();

        if (k < 64) {
            const float ig = gsh[k];
            const float fg = gsh[64 + k];
            const float gg = gsh[128 + k];
            const float og = gsh[192 + k];
            c = fmaf(fg, c, ig * gg);
            const float h = og * tanh_f(c);
            hsh[k] = h;
            const long row = rowbase + t;
            if (LAYER == 1) out[row * 256 + k * 4 + g] = h;       // interleaved f = h*4+g
            else            out[row * 256 + colbase + k] = h;     // contiguous f = g*64+h
            xsh[cur ^ 1][k] = fmaf(xa, af, cf);  // af=1,cf=0 for layer1
            xa = xb; xb = xn;
        }
        __syncthreads();
    }
}

__global__ void zero_ws(float* sums) {
    int i = blockIdx.x * blockDim.x + threadIdx.x;
    if (i < 512) sums[i] = 0.f;
}

// Per-feature sum / sumsq over (B,T). Thread f accumulates its feature over
// rows (fully coalesced, register accumulators), one atomicAdd per thread.
__global__ __launch_bounds__(256) void stats_reduce(const float* __restrict__ x,
                                                    float* __restrict__ sums)
{
    float s = 0.f, ss = 0.f;
    for (int r = blockIdx.x; r < ROWS; r += gridDim.x) {
        float v = x[(long)r * 256 + threadIdx.x];
        s += v;
        ss = fmaf(v, v, ss);
    }
    atomicAdd(&sums[threadIdx.x], s);
    atomicAdd(&sums[256 + threadIdx.x], ss);
}

__global__ void stats_finalize(const float* __restrict__ sums,
                               const float* __restrict__ gamma,
                               const float* __restrict__ beta,
                               float* __restrict__ ac)
{
    int f = threadIdx.x;
    const float invN = 1.f / (float)ROWS;
    float mean = sums[f] * invN;
    float var  = fmaf(-mean, mean, sums[256 + f] * invN);  // biased (ddof=0)
    float a = gamma[f] * rsqrtf(var + 1e-5f);
    ac[f]       = a;
    ac[256 + f] = fmaf(-mean, a, beta[f]);
}

__global__ __launch_bounds__(256) void bn_apply(float* __restrict__ x,
                                                const float* __restrict__ ac)
{
    __shared__ float a_s[256], c_s[256];
    a_s[threadIdx.x] = ac[threadIdx.x];
    c_s[threadIdx.x] = ac[256 + threadIdx.x];
    __syncthreads();
    const long n4 = (long)ROWS * 64;  // total float4s
    for (long i = (long)blockIdx.x * blockDim.x + threadIdx.x; i < n4;
         i += (long)gridDim.x * blockDim.x) {
        float4 v = ((float4*)x)[i];
        int f0 = (int)((i * 4) & 255);
        v.x = fmaf(v.x, a_s[f0],     c_s[f0]);
        v.y = fmaf(v.y, a_s[f0 + 1], c_s[f0 + 1]);
        v.z = fmaf(v.z, a_s[f0 + 2], c_s[f0 + 2]);
        v.w = fmaf(v.w, a_s[f0 + 3], c_s[f0 + 3]);
        ((float4*)x)[i] = v;
    }
}

extern "C" void kernel_launch(void* const* d_in, const int* in_sizes, int n_in,
                              void* d_out, int out_size, void* d_ws, size_t ws_size,
                              hipStream_t stream)
{
    const float* inpt   = (const float*)d_in[0];
    const float* Wih1   = (const float*)d_in[1];
    const float* Whh1   = (const float*)d_in[2];
    const float* b1     = (const float*)d_in[3];
    const float* Wih2   = (const float*)d_in[4];
    const float* Whh2   = (const float*)d_in[5];
    const float* b2     = (const float*)d_in[6];
    const float* gamma1 = (const float*)d_in[7];
    const float* beta1  = (const float*)d_in[8];
    const float* gamma2 = (const float*)d_in[9];
    const float* beta2  = (const float*)d_in[10];
    float* out  = (float*)d_out;
    float* sums = (float*)d_ws;     // [512]
    float* ac   = sums + 512;       // [512]

    // Layer 1 LSTM -> d_out (interleaved features h*4+g)
    zero_ws<<<2, 256, 0, stream>>>(sums);
    rec_kernel<1><<<G * B, 256, 0, stream>>>(inpt, Wih1, Whh1, b1, nullptr, out);

    // BN1 stats -> scale/shift
    stats_reduce<<<256, 256, 0, stream>>>(out, sums);
    stats_finalize<<<1, 256, 0, stream>>>(sums, gamma1, beta1, ac);

    // Layer 2 LSTM: reads d_out with BN1 fused, overwrites d_out (contiguous g*64+h)
    rec_kernel<2><<<G * B, 256, 0, stream>>>(out, Wih2, Whh2, b2, ac, out);

    // BN2 stats + in-place apply
    zero_ws<<<2, 256, 0, stream>>>(sums);
    stats_reduce<<<256, 256, 0, stream>>>(out, sums);
    stats_finalize<<<1, 256, 0, stream>>>(sums, gamma2, beta2, ac);
    bn_apply<<<2048, 256, 0, stream>>>(out, ac);
}